// Round 9
// baseline (187.156 us; speedup 1.0000x reference)
//
#include <hip/hip_runtime.h>
#include <math.h>

#define BATCH 16
#define SEQ   720
#define ENC   321
#define NORD  64
#define PRED  720
#define NPAIR (BATCH*ENC)    // 5136

// ---- ws layout (float offsets); ws is 256 MiB, we use ~6.8 MB ----
#define WS_KT    0                         // 720x64: Kt[t][m] = (A^(719-t) B)[m]
#define WS_EWT   (WS_KT + PRED*NORD)       // 64x720: EW^T [m][t']
#define WS_EVB   (WS_EWT + NORD*PRED)      // 720
#define WS_KSUM  (WS_EVB + PRED)           // 64: sum_t Kt[t][m]
#define WS_G     (WS_KSUM + 64)            // 4 tsp x 96 (b*6+et) x 4096, m-major [m][el]
#define WS_PSUM  (WS_G + 4*96*4096)        // 4*16*6*64
#define WS_PSS   (WS_PSUM + 4*16*6*64)

// ============ prep: [bid<12] EW^T + evb | [bid==12] Krylov A^64 + chains + Ksum ============
__global__ __launch_bounds__(1024) void prep(const float* __restrict__ evalm,
        const float* __restrict__ W, const float* __restrict__ bm,
        const float* __restrict__ A, const float* __restrict__ Bv,
        float* __restrict__ ws)
{
    __shared__ float dsm[12800];     // 51.2 KB arena, aliased per role
    const int tid  = threadIdx.x;
    const int lane = tid & 63;
    const int wv   = tid >> 6;       // 0..15
    if (blockIdx.x < 12) {
        float* smW = dsm;            // [n][m] pad 65 (4160)
        float* Et  = dsm + 4160;     // [m][row] pad 61 (3904)
        const int r = blockIdx.x;
        for (int idx = tid; idx < 4096; idx += 1024)
            smW[(idx>>6)*65 + (idx&63)] = W[idx];
        __syncthreads();
        float bv = bm[lane];
        #pragma unroll
        for (int k = 0; k < 4; k++) {
            int row = wv + k*16;
            if (row < 60) {
                int tp = r*60 + row;
                const float* ev = evalm + (size_t)tp*64;
                float acc = 0.f;
                #pragma unroll
                for (int kk = 0; kk < 16; kk++) {
                    float4 e4 = *(const float4*)&ev[4*kk];
                    acc += e4.x*smW[(4*kk+0)*65+lane] + e4.y*smW[(4*kk+1)*65+lane]
                         + e4.z*smW[(4*kk+2)*65+lane] + e4.w*smW[(4*kk+3)*65+lane];
                }
                Et[lane*61 + row] = acc;
                float pv = ev[lane] * bv;
                #pragma unroll
                for (int o = 32; o > 0; o >>= 1) pv += __shfl_down(pv, o);
                if (lane == 0) ws[WS_EVB + tp] = pv;
            }
        }
        __syncthreads();
        #pragma unroll
        for (int k = 0; k < 4; k++) {
            int idx = k*1024 + tid;
            int m = idx >> 6, row = idx & 63;
            if (row < 60)
                ws[WS_EWT + (size_t)m*720 + r*60 + row] = Et[m*61 + row];
        }
    } else {
        float* Kl  = dsm;            // [64][64] rows j=0..63 (4096)
        float* Ap  = dsm + 4096;     // [64][68] A^m
        float* ApT = dsm + 8448;     // [64][68] (A^m)^T; later: per-wave chain vectors
        float* Kt  = ws + WS_KT;
        for (int idx = tid; idx < 4096; idx += 1024) {
            int n = idx >> 6, m = idx & 63;
            float v = A[idx];
            Ap[n*68+m] = v; ApT[m*68+n] = v;
        }
        float ksml = 0.f;            // per-thread partial of Ksum[lane]
        if (tid < 64) {
            float bv = Bv[tid];
            Kl[tid] = bv;
            Kt[(size_t)719*64 + tid] = bv;
            ksml += bv;              // row j=0
        }
        __syncthreads();
        float ar[64];                // row `lane` of A^m
        #pragma unroll
        for (int k = 0; k < 16; k++) {
            float4 v = *(const float4*)&Ap[lane*68 + 4*k];
            ar[4*k]=v.x; ar[4*k+1]=v.y; ar[4*k+2]=v.z; ar[4*k+3]=v.w;
        }
        for (int mm = 1; mm <= 32; mm <<= 1) {
            // expand rows mm..2mm-1:  K[j2] = A^mm @ K[j2-mm]
            for (int j2 = mm + wv; j2 < 2*mm; j2 += 16) {
                const float* src = &Kl[(j2 - mm)*64];
                float acc = 0.f;
                #pragma unroll
                for (int k = 0; k < 16; k++) {
                    float4 s = *(const float4*)&src[4*k];   // wave-uniform broadcast
                    acc += ar[4*k]*s.x + ar[4*k+1]*s.y + ar[4*k+2]*s.z + ar[4*k+3]*s.w;
                }
                Kl[j2*64 + lane] = acc;
                Kt[(size_t)(719 - j2)*64 + lane] = acc;
                ksml += acc;                                // rows 1..63, each once
            }
            // square: A^(2mm) = A^mm @ A^mm
            float nacc[4];
            #pragma unroll
            for (int q = 0; q < 4; q++) {
                int c = wv*4 + q;
                const float* src = &ApT[c*68];
                float acc = 0.f;
                #pragma unroll
                for (int k = 0; k < 16; k++) {
                    float4 s = *(const float4*)&src[4*k];
                    acc += ar[4*k]*s.x + ar[4*k+1]*s.y + ar[4*k+2]*s.z + ar[4*k+3]*s.w;
                }
                nacc[q] = acc;
            }
            __syncthreads();
            #pragma unroll
            for (int q = 0; q < 4; q++) {
                int c = wv*4 + q;
                Ap[lane*68 + c]  = nacc[q];
                ApT[c*68 + lane] = nacc[q];
            }
            __syncthreads();
            #pragma unroll
            for (int k = 0; k < 16; k++) {
                float4 v = *(const float4*)&Ap[lane*68 + 4*k];
                ar[4*k]=v.x; ar[4*k+1]=v.y; ar[4*k+2]=v.z; ar[4*k+3]=v.w;
            }
        }
        // ar now holds A^64. Chains: 64 chains, wave wv does r = wv+16c, c=0..3.
        float* sv = &ApT[wv*68];     // ApT no longer needed
        #pragma unroll
        for (int c = 0; c < 4; c++) {
            const int r = wv + 16*c;
            sv[lane] = Kl[r*64 + lane];            // seed K[r] (Kl stable during chains)
            for (int j = r + 64; j <= 719; j += 64) {
                float acc = 0.f;
                #pragma unroll
                for (int k = 0; k < 16; k++) {
                    float4 v = *(const float4*)&sv[4*k];
                    acc += ar[4*k]*v.x + ar[4*k+1]*v.y + ar[4*k+2]*v.z + ar[4*k+3]*v.w;
                }
                sv[lane] = acc;                    // same-wave DS ordering
                Kt[(size_t)(719 - j)*64 + lane] = acc;
                ksml += acc;                       // rows 64..719, each once
            }
        }
        __syncthreads();                           // all chains (and Kl seed reads) done
        Kl[wv*64 + lane] = ksml;                   // reuse Kl for 16-way reduce
        __syncthreads();
        if (tid < 64) {
            float s = 0.f;
            #pragma unroll
            for (int k = 0; k < 16; k++) s += Kl[k*64 + tid];
            ws[WS_KSUM + tid] = s;
        }
    }
}

// ============ k2: G[m][el] slabs (m-major) + stats partials; no atomics ============
__device__ inline float4 ldx(const float* __restrict__ x, int b, int t, int e4)
{
    float4 r = make_float4(0.f,0.f,0.f,0.f);
    const float* p = x + ((size_t)b*SEQ + t)*ENC;
    if (e4 + 3 < ENC) r = *(const float4*)&p[e4];
    else {
        if (e4   < ENC) r.x = p[e4];
        if (e4+1 < ENC) r.y = p[e4+1];
        if (e4+2 < ENC) r.z = p[e4+2];
    }
    return r;
}

__global__ __launch_bounds__(256) void k2(const float* __restrict__ x,
        float* __restrict__ ws)
{
    __shared__ float xt[2][12*64];
    __shared__ float ks[2][12*64];
    __shared__ float redn[12*64];
    __shared__ float reds[12*64];
    const int tid = threadIdx.x;
    const int bid = blockIdx.x;
    const int b = bid / 24, rem = bid % 24;
    const int et = rem / 4, tsp = rem % 4;
    const int e0 = et*64, t0 = tsp*180;

    const bool xon = tid < 192;
    const bool kon = tid >= 64;
    const int sx_t  = tid >> 4;
    const int sx_e4 = (tid & 15) * 4;
    const int sk    = tid - 64;
    const int sk_t  = sk >> 4;
    const int sk_m4 = (sk & 15) * 4;

    const float* Kt = ws + WS_KT;
    float s0=0,s1=0,s2=0,s3=0, q0=0,q1=0,q2=0,q3=0;
    float4 rx = make_float4(0,0,0,0), rk = make_float4(0,0,0,0);

    if (xon) rx = ldx(x, b, t0 + sx_t, e0 + sx_e4);
    if (kon) rk = *(const float4*)&Kt[(size_t)(t0 + sk_t)*64 + sk_m4];
    if (xon) {
        *(float4*)&xt[0][sx_t*64 + sx_e4] = rx;
        s0+=rx.x; s1+=rx.y; s2+=rx.z; s3+=rx.w;
        q0+=rx.x*rx.x; q1+=rx.y*rx.y; q2+=rx.z*rx.z; q3+=rx.w*rx.w;
    }
    if (kon) *(float4*)&ks[0][sk_t*64 + sk_m4] = rk;

    const int lane = tid & 63, wv = tid >> 6;
    const int elg = lane & 15;            // el = elg*4 + j
    const int mgr = wv*4 + (lane >> 4);   // m  = mgr*4 + i
    float acc[4][4];                      // [e comp][m comp]
    #pragma unroll
    for (int j = 0; j < 4; j++)
        #pragma unroll
        for (int i = 0; i < 4; i++) acc[j][i] = 0.f;

    for (int ch = 0; ch < 15; ch++) {
        if (ch + 1 < 15) {
            if (xon) rx = ldx(x, b, t0 + (ch+1)*12 + sx_t, e0 + sx_e4);
            if (kon) rk = *(const float4*)&Kt[(size_t)(t0 + (ch+1)*12 + sk_t)*64 + sk_m4];
        }
        __syncthreads();
        const float* xb = xt[ch & 1];
        const float* kb = ks[ch & 1];
        #pragma unroll
        for (int tt = 0; tt < 12; tt++) {
            float4 f  = *(const float4*)&xb[tt*64 + elg*4];
            float4 kv = *(const float4*)&kb[tt*64 + mgr*4];
            acc[0][0]+=f.x*kv.x; acc[0][1]+=f.x*kv.y; acc[0][2]+=f.x*kv.z; acc[0][3]+=f.x*kv.w;
            acc[1][0]+=f.y*kv.x; acc[1][1]+=f.y*kv.y; acc[1][2]+=f.y*kv.z; acc[1][3]+=f.y*kv.w;
            acc[2][0]+=f.z*kv.x; acc[2][1]+=f.z*kv.y; acc[2][2]+=f.z*kv.z; acc[2][3]+=f.z*kv.w;
            acc[3][0]+=f.w*kv.x; acc[3][1]+=f.w*kv.y; acc[3][2]+=f.w*kv.z; acc[3][3]+=f.w*kv.w;
        }
        if (ch + 1 < 15) {
            if (xon) {
                *(float4*)&xt[(ch+1)&1][sx_t*64 + sx_e4] = rx;
                s0+=rx.x; s1+=rx.y; s2+=rx.z; s3+=rx.w;
                q0+=rx.x*rx.x; q1+=rx.y*rx.y; q2+=rx.z*rx.z; q3+=rx.w*rx.w;
            }
            if (kon) *(float4*)&ks[(ch+1)&1][sk_t*64 + sk_m4] = rk;
        }
    }

    // m-major slab write: row m = mgr*4+i, float4 over el — fully coalesced
    float* g = ws + WS_G + (size_t)(tsp*96 + b*6 + et)*4096;
    #pragma unroll
    for (int i = 0; i < 4; i++)
        *(float4*)&g[(mgr*4 + i)*64 + elg*4] =
            make_float4(acc[0][i], acc[1][i], acc[2][i], acc[3][i]);

    __syncthreads();
    if (xon) {
        redn[sx_t*64 + sx_e4+0] = s0; redn[sx_t*64 + sx_e4+1] = s1;
        redn[sx_t*64 + sx_e4+2] = s2; redn[sx_t*64 + sx_e4+3] = s3;
        reds[sx_t*64 + sx_e4+0] = q0; reds[sx_t*64 + sx_e4+1] = q1;
        reds[sx_t*64 + sx_e4+2] = q2; reds[sx_t*64 + sx_e4+3] = q3;
    }
    __syncthreads();
    if (tid < 64) {
        float s = 0.f, q = 0.f;
        #pragma unroll
        for (int rr = 0; rr < 12; rr++) { s += redn[rr*64 + tid]; q += reds[rr*64 + tid]; }
        const size_t o = (size_t)((tsp*16 + b)*6 + et)*64 + tid;
        ws[WS_PSUM + o] = s;
        ws[WS_PSS  + o] = q;
    }
}

// ============ k3f: fused (k2b + k3) — slabs+stats -> Cm in LDS -> out, denorm ============
// grid 192 = 16b x 3 e-tiles(128) x 4 t-quarters (3 t'-tiles of 64 each); 256 thr.
__global__ __launch_bounds__(256) void k3f(const float* __restrict__ aw,
        const float* __restrict__ ab, const float* __restrict__ ws,
        float* __restrict__ out)
{
    __shared__ float Cm[64*132];     // [m][e 128] (pad 132, 16B-aligned rows)
    __shared__ float EWm[64*68];     // [m][t' 64]
    __shared__ float ssc[128], ssh[128], smean[128], ssd[128], siaw[128], sabe[128];
    __shared__ float kss[64];
    const int tid = threadIdx.x;
    const int b   = blockIdx.x / 12;
    const int rr  = blockIdx.x % 12;
    const int eT  = rr / 4;          // 0..2
    const int tq  = rr % 4;          // 0..3
    const int e0  = eT * 128;
    const int et0 = eT * 2;

    if (tid < 128) {
        const int el = tid, e = e0 + el;
        const int et = et0 + (el >> 6), eli = el & 63;
        float s = 0.f, q = 0.f;
        #pragma unroll
        for (int tsp = 0; tsp < 4; tsp++) {
            const size_t o = (size_t)((tsp*16 + b)*6 + et)*64 + eli;
            s += ws[WS_PSUM + o];
            q += ws[WS_PSS  + o];
        }
        float mean = s * (1.0f/SEQ);
        float var  = q * (1.0f/SEQ) - mean*mean;
        float sd   = sqrtf(var + 1e-5f);
        if (e < ENC) {
            float a = aw[e], av = ab[e];
            float sc = a / sd;
            ssc[el] = sc; ssh[el] = av - mean*sc;
            smean[el] = mean; ssd[el] = sd;
            siaw[el] = 1.0f/(a + 1e-10f); sabe[el] = av;
        } else {
            ssc[el]=0.f; ssh[el]=0.f; smean[el]=0.f; ssd[el]=0.f; siaw[el]=0.f; sabe[el]=0.f;
        }
    }
    if (tid < 64) kss[tid] = ws[WS_KSUM + tid];
    __syncthreads();

    // Cm[m][el] = ssc[el]*(sum of 4 tsp slabs)[m][el] + ssh[el]*Ksum[m]
    const float* G = ws + WS_G;
    #pragma unroll
    for (int k = 0; k < 8; k++) {
        int slot = k*256 + tid;
        int m = slot >> 5, el4 = (slot & 31) * 4;
        int et = et0 + (el4 >> 6), eli4 = el4 & 63;
        size_t base = (size_t)(b*6 + et)*4096 + m*64 + eli4;
        float4 g0 = *(const float4*)&G[base];
        float4 g1 = *(const float4*)&G[base + (size_t) 96*4096];
        float4 g2 = *(const float4*)&G[base + (size_t)192*4096];
        float4 g3 = *(const float4*)&G[base + (size_t)288*4096];
        float km = kss[m];
        float4 c;
        c.x = ssc[el4+0]*(g0.x+g1.x+g2.x+g3.x) + ssh[el4+0]*km;
        c.y = ssc[el4+1]*(g0.y+g1.y+g2.y+g3.y) + ssh[el4+1]*km;
        c.z = ssc[el4+2]*(g0.z+g1.z+g2.z+g3.z) + ssh[el4+2]*km;
        c.w = ssc[el4+3]*(g0.w+g1.w+g2.w+g3.w) + ssh[el4+3]*km;
        *(float4*)&Cm[m*132 + el4] = c;
    }
    __syncthreads();

    const float* EWT = ws + WS_EWT;
    const float* evb = ws + WS_EVB;
    const int tx = tid & 31;
    const int ty = tid >> 5;
    for (int ti = 0; ti < 3; ti++) {
        const int tt0 = (tq*3 + ti) * 64;
        if (ti > 0) __syncthreads();       // prior compute done before EWm restage
        #pragma unroll
        for (int k = 0; k < 4; k++) {
            int slot = k*256 + tid;
            int m = slot >> 4, t4 = (slot & 15)*4;
            int tp = tt0 + t4;
            float4 v;
            if (tp + 3 < PRED) v = *(const float4*)&EWT[(size_t)m*720 + tp];
            else {
                v = make_float4(0.f,0.f,0.f,0.f);
                if (tp   < PRED) v.x = EWT[(size_t)m*720 + tp];
                if (tp+1 < PRED) v.y = EWT[(size_t)m*720 + tp+1];
                if (tp+2 < PRED) v.z = EWT[(size_t)m*720 + tp+2];
            }
            *(float4*)&EWm[m*68 + t4] = v;
        }
        __syncthreads();

        float acc[8][4];
        #pragma unroll
        for (int i = 0; i < 8; i++)
            #pragma unroll
            for (int j = 0; j < 4; j++) acc[i][j] = 0.f;

        #pragma unroll 4
        for (int m = 0; m < 64; m++) {
            float4 c4 = *(const float4*)&Cm[m*132 + tx*4];
            float4 w0 = *(const float4*)&EWm[m*68 + ty*8];
            float4 w1 = *(const float4*)&EWm[m*68 + ty*8 + 4];
            acc[0][0]+=w0.x*c4.x; acc[0][1]+=w0.x*c4.y; acc[0][2]+=w0.x*c4.z; acc[0][3]+=w0.x*c4.w;
            acc[1][0]+=w0.y*c4.x; acc[1][1]+=w0.y*c4.y; acc[1][2]+=w0.y*c4.z; acc[1][3]+=w0.y*c4.w;
            acc[2][0]+=w0.z*c4.x; acc[2][1]+=w0.z*c4.y; acc[2][2]+=w0.z*c4.z; acc[2][3]+=w0.z*c4.w;
            acc[3][0]+=w0.w*c4.x; acc[3][1]+=w0.w*c4.y; acc[3][2]+=w0.w*c4.z; acc[3][3]+=w0.w*c4.w;
            acc[4][0]+=w1.x*c4.x; acc[4][1]+=w1.x*c4.y; acc[4][2]+=w1.x*c4.z; acc[4][3]+=w1.x*c4.w;
            acc[5][0]+=w1.y*c4.x; acc[5][1]+=w1.y*c4.y; acc[5][2]+=w1.y*c4.z; acc[5][3]+=w1.y*c4.w;
            acc[6][0]+=w1.z*c4.x; acc[6][1]+=w1.z*c4.y; acc[6][2]+=w1.z*c4.z; acc[6][3]+=w1.z*c4.w;
            acc[7][0]+=w1.w*c4.x; acc[7][1]+=w1.w*c4.y; acc[7][2]+=w1.w*c4.z; acc[7][3]+=w1.w*c4.w;
        }

        const int elb = tx*4;
        const int ebase = e0 + elb;
        #pragma unroll
        for (int i = 0; i < 8; i++) {
            int tp = tt0 + ty*8 + i;
            if (tp < PRED) {
                float ev = evb[tp];
                float* op = out + ((size_t)b*PRED + tp)*ENC;
                #pragma unroll
                for (int j = 0; j < 4; j++) {
                    int e = ebase + j;
                    if (e < ENC)
                        op[e] = (acc[i][j] + ev - sabe[elb+j]) * siaw[elb+j] * ssd[elb+j]
                                + smean[elb+j];
                }
            }
        }
    }
}

extern "C" void kernel_launch(void* const* d_in, const int* in_sizes, int n_in,
                              void* d_out, int out_size, void* d_ws, size_t ws_size,
                              hipStream_t stream)
{
    const float* x     = (const float*)d_in[0];
    const float* A     = (const float*)d_in[1];
    const float* Bv    = (const float*)d_in[2];
    const float* evalm = (const float*)d_in[3];
    const float* W     = (const float*)d_in[4];
    const float* bm    = (const float*)d_in[5];
    const float* aw    = (const float*)d_in[6];
    const float* ab    = (const float*)d_in[7];
    float* ws  = (float*)d_ws;
    float* out = (float*)d_out;

    prep<<<13, 1024, 0, stream>>>(evalm, W, bm, A, Bv, ws);
    k2  <<<BATCH*6*4, 256, 0, stream>>>(x, ws);
    k3f <<<192, 256, 0, stream>>>(aw, ab, ws, out);
}

// Round 10
// 178.224 us; speedup vs baseline: 1.0501x; 1.0501x over previous
//
#include <hip/hip_runtime.h>
#include <math.h>

#define BATCH 16
#define SEQ   720
#define ENC   321
#define NORD  64
#define PRED  720
#define NPAIR (BATCH*ENC)    // 5136

// ---- ws layout (float offsets) ----
#define WS_KT    0                         // 720x64: Kt[t][m] = (A^(719-t) B)[m]
#define WS_EWT   (WS_KT + PRED*NORD)       // 64x720: EW^T [m][t']
#define WS_EVB   (WS_EWT + NORD*PRED)      // 720
#define WS_A64   (WS_EVB + PRED)           // 64x64
#define WS_KSUMP (WS_A64 + 4096)           // 17x64 Ksum partials (16 chain blocks + 1 prep)
#define WS_G     (WS_KSUMP + 17*64)        // 4 tsp x 96 x 4096, m-major [m][el]
#define WS_PSUM  (WS_G + 4*96*4096)
#define WS_PSS   (WS_PSUM + 4*16*6*64)

// ============ prep2 (256 thr!): [bid<12] EW^T + evb | [bid==12] squaring -> A^64 ============
// 256 threads so ar[64] fits in VGPRs (R9 post-mortem: 1024-thr cap=64 VGPR spilled ar -> 63us).
__global__ __launch_bounds__(256, 1) void prep2(const float* __restrict__ evalm,
        const float* __restrict__ W, const float* __restrict__ bm,
        const float* __restrict__ A, const float* __restrict__ Bv,
        float* __restrict__ ws)
{
    __shared__ float dsm[12800];
    const int tid  = threadIdx.x;
    const int lane = tid & 63;
    const int wv   = tid >> 6;       // 0..3
    if (blockIdx.x < 12) {
        float* smW = dsm;            // [n][m] pad 65 (4160)
        float* Et  = dsm + 4160;     // [m][row] pad 61
        const int r = blockIdx.x;
        for (int idx = tid; idx < 4096; idx += 256)
            smW[(idx>>6)*65 + (idx&63)] = W[idx];
        __syncthreads();
        float bv = bm[lane];
        #pragma unroll
        for (int k = 0; k < 15; k++) {
            int row = wv + k*4;              // rows 0..59
            int tp = r*60 + row;
            const float* ev = evalm + (size_t)tp*64;
            float acc = 0.f;
            #pragma unroll
            for (int kk = 0; kk < 16; kk++) {
                float4 e4 = *(const float4*)&ev[4*kk];
                acc += e4.x*smW[(4*kk+0)*65+lane] + e4.y*smW[(4*kk+1)*65+lane]
                     + e4.z*smW[(4*kk+2)*65+lane] + e4.w*smW[(4*kk+3)*65+lane];
            }
            Et[lane*61 + row] = acc;
            float pv = ev[lane] * bv;
            #pragma unroll
            for (int o = 32; o > 0; o >>= 1) pv += __shfl_down(pv, o);
            if (lane == 0) ws[WS_EVB + tp] = pv;
        }
        __syncthreads();
        for (int idx = tid; idx < 4096; idx += 256) {
            int m = idx >> 6, row = idx & 63;
            if (row < 60)
                ws[WS_EWT + (size_t)m*720 + r*60 + row] = Et[m*61 + row];
        }
    } else {
        float* Kl  = dsm;            // [64][64] rows j=0..63
        float* Ap  = dsm + 4096;     // [64][68] A^m
        float* ApT = dsm + 8448;     // [64][68] (A^m)^T
        float* Kt  = ws + WS_KT;
        for (int idx = tid; idx < 4096; idx += 256) {
            int n = idx >> 6, m = idx & 63;
            float v = A[idx];
            Ap[n*68+m] = v; ApT[m*68+n] = v;
        }
        float ksml = 0.f;            // partial of Ksum[lane] (rows 0..63)
        if (tid < 64) {
            float bv = Bv[tid];
            Kl[tid] = bv;
            Kt[(size_t)719*64 + tid] = bv;
            ksml += bv;              // row 0
        }
        __syncthreads();
        float ar[64];                // row `lane` of A^m — MUST stay in VGPRs
        #pragma unroll
        for (int k = 0; k < 16; k++) {
            float4 v = *(const float4*)&Ap[lane*68 + 4*k];
            ar[4*k]=v.x; ar[4*k+1]=v.y; ar[4*k+2]=v.z; ar[4*k+3]=v.w;
        }
        for (int mm = 1; mm <= 32; mm <<= 1) {
            // expand rows mm..2mm-1:  K[j2] = A^mm @ K[j2-mm]
            for (int j2 = mm + wv; j2 < 2*mm; j2 += 4) {
                const float* src = &Kl[(j2 - mm)*64];
                float acc = 0.f;
                #pragma unroll
                for (int k = 0; k < 16; k++) {
                    float4 s = *(const float4*)&src[4*k];   // wave-uniform broadcast
                    acc += ar[4*k]*s.x + ar[4*k+1]*s.y + ar[4*k+2]*s.z + ar[4*k+3]*s.w;
                }
                Kl[j2*64 + lane] = acc;
                Kt[(size_t)(719 - j2)*64 + lane] = acc;
                ksml += acc;                                // rows 1..63, each once
            }
            // square: A^(2mm) = A^mm @ A^mm ; wave handles 16 columns
            float nacc[16];
            #pragma unroll
            for (int q = 0; q < 16; q++) {
                int c = wv*16 + q;
                const float* src = &ApT[c*68];
                float acc = 0.f;
                #pragma unroll
                for (int k = 0; k < 16; k++) {
                    float4 s = *(const float4*)&src[4*k];
                    acc += ar[4*k]*s.x + ar[4*k+1]*s.y + ar[4*k+2]*s.z + ar[4*k+3]*s.w;
                }
                nacc[q] = acc;
            }
            __syncthreads();
            #pragma unroll
            for (int q = 0; q < 16; q++) {
                int c = wv*16 + q;
                Ap[lane*68 + c]  = nacc[q];
                ApT[c*68 + lane] = nacc[q];
            }
            __syncthreads();
            #pragma unroll
            for (int k = 0; k < 16; k++) {
                float4 v = *(const float4*)&Ap[lane*68 + 4*k];
                ar[4*k]=v.x; ar[4*k+1]=v.y; ar[4*k+2]=v.z; ar[4*k+3]=v.w;
            }
        }
        // write A^64 for the chains kernel
        for (int idx = tid; idx < 4096; idx += 256)
            ws[WS_A64 + idx] = Ap[(idx>>6)*68 + (idx&63)];
        // Ksum partial slot 16 (rows 0..63)
        __syncthreads();
        Kl[wv*64 + lane] = ksml;
        __syncthreads();
        if (tid < 64)
            ws[WS_KSUMP + 16*64 + tid] = Kl[tid] + Kl[64+tid] + Kl[128+tid] + Kl[192+tid];
    }
}

// ============ chains: 64 chains K[r+64q] = A^64 K[r+64(q-1)]; Ksum partials ============
// 16 blocks x 256 thr, 1 chain per wave, <=11 serial steps; ar64 in VGPRs.
__global__ __launch_bounds__(256, 1) void chains(float* __restrict__ ws)
{
    __shared__ float sv[4][64];
    __shared__ float red[4][64];
    const int tid  = threadIdx.x;
    const int lane = tid & 63;
    const int wv   = tid >> 6;
    const int r    = blockIdx.x*4 + wv;          // chain 0..63
    const float* A64 = ws + WS_A64;
    float* Kt = ws + WS_KT;
    float ar64[64];
    #pragma unroll
    for (int k = 0; k < 16; k++) {
        float4 v = *(const float4*)&A64[lane*64 + 4*k];
        ar64[4*k]=v.x; ar64[4*k+1]=v.y; ar64[4*k+2]=v.z; ar64[4*k+3]=v.w;
    }
    float ksml = 0.f;
    sv[wv][lane] = Kt[(size_t)(719 - r)*64 + lane];   // seed K[r]
    for (int j = r + 64; j <= 719; j += 64) {
        float acc = 0.f;
        #pragma unroll
        for (int k = 0; k < 16; k++) {
            float4 v = *(const float4*)&sv[wv][4*k];
            acc += ar64[4*k]*v.x + ar64[4*k+1]*v.y + ar64[4*k+2]*v.z + ar64[4*k+3]*v.w;
        }
        sv[wv][lane] = acc;                           // same-wave DS ordering
        Kt[(size_t)(719 - j)*64 + lane] = acc;
        ksml += acc;                                  // rows 64..719, each once
    }
    red[wv][lane] = ksml;
    __syncthreads();
    if (tid < 64)
        ws[WS_KSUMP + blockIdx.x*64 + tid] = red[0][tid] + red[1][tid] + red[2][tid] + red[3][tid];
}

// ============ k2: G[m][el] slabs (m-major) + stats partials; no atomics (unchanged) ============
__device__ inline float4 ldx(const float* __restrict__ x, int b, int t, int e4)
{
    float4 r = make_float4(0.f,0.f,0.f,0.f);
    const float* p = x + ((size_t)b*SEQ + t)*ENC;
    if (e4 + 3 < ENC) r = *(const float4*)&p[e4];
    else {
        if (e4   < ENC) r.x = p[e4];
        if (e4+1 < ENC) r.y = p[e4+1];
        if (e4+2 < ENC) r.z = p[e4+2];
    }
    return r;
}

__global__ __launch_bounds__(256) void k2(const float* __restrict__ x,
        float* __restrict__ ws)
{
    __shared__ float xt[2][12*64];
    __shared__ float ks[2][12*64];
    __shared__ float redn[12*64];
    __shared__ float reds[12*64];
    const int tid = threadIdx.x;
    const int bid = blockIdx.x;
    const int b = bid / 24, rem = bid % 24;
    const int et = rem / 4, tsp = rem % 4;
    const int e0 = et*64, t0 = tsp*180;

    const bool xon = tid < 192;
    const bool kon = tid >= 64;
    const int sx_t  = tid >> 4;
    const int sx_e4 = (tid & 15) * 4;
    const int sk    = tid - 64;
    const int sk_t  = sk >> 4;
    const int sk_m4 = (sk & 15) * 4;

    const float* Kt = ws + WS_KT;
    float s0=0,s1=0,s2=0,s3=0, q0=0,q1=0,q2=0,q3=0;
    float4 rx = make_float4(0,0,0,0), rk = make_float4(0,0,0,0);

    if (xon) rx = ldx(x, b, t0 + sx_t, e0 + sx_e4);
    if (kon) rk = *(const float4*)&Kt[(size_t)(t0 + sk_t)*64 + sk_m4];
    if (xon) {
        *(float4*)&xt[0][sx_t*64 + sx_e4] = rx;
        s0+=rx.x; s1+=rx.y; s2+=rx.z; s3+=rx.w;
        q0+=rx.x*rx.x; q1+=rx.y*rx.y; q2+=rx.z*rx.z; q3+=rx.w*rx.w;
    }
    if (kon) *(float4*)&ks[0][sk_t*64 + sk_m4] = rk;

    const int lane = tid & 63, wv = tid >> 6;
    const int elg = lane & 15;            // el = elg*4 + j
    const int mgr = wv*4 + (lane >> 4);   // m  = mgr*4 + i
    float acc[4][4];
    #pragma unroll
    for (int j = 0; j < 4; j++)
        #pragma unroll
        for (int i = 0; i < 4; i++) acc[j][i] = 0.f;

    for (int ch = 0; ch < 15; ch++) {
        if (ch + 1 < 15) {
            if (xon) rx = ldx(x, b, t0 + (ch+1)*12 + sx_t, e0 + sx_e4);
            if (kon) rk = *(const float4*)&Kt[(size_t)(t0 + (ch+1)*12 + sk_t)*64 + sk_m4];
        }
        __syncthreads();
        const float* xb = xt[ch & 1];
        const float* kb = ks[ch & 1];
        #pragma unroll
        for (int tt = 0; tt < 12; tt++) {
            float4 f  = *(const float4*)&xb[tt*64 + elg*4];
            float4 kv = *(const float4*)&kb[tt*64 + mgr*4];
            acc[0][0]+=f.x*kv.x; acc[0][1]+=f.x*kv.y; acc[0][2]+=f.x*kv.z; acc[0][3]+=f.x*kv.w;
            acc[1][0]+=f.y*kv.x; acc[1][1]+=f.y*kv.y; acc[1][2]+=f.y*kv.z; acc[1][3]+=f.y*kv.w;
            acc[2][0]+=f.z*kv.x; acc[2][1]+=f.z*kv.y; acc[2][2]+=f.z*kv.z; acc[2][3]+=f.z*kv.w;
            acc[3][0]+=f.w*kv.x; acc[3][1]+=f.w*kv.y; acc[3][2]+=f.w*kv.z; acc[3][3]+=f.w*kv.w;
        }
        if (ch + 1 < 15) {
            if (xon) {
                *(float4*)&xt[(ch+1)&1][sx_t*64 + sx_e4] = rx;
                s0+=rx.x; s1+=rx.y; s2+=rx.z; s3+=rx.w;
                q0+=rx.x*rx.x; q1+=rx.y*rx.y; q2+=rx.z*rx.z; q3+=rx.w*rx.w;
            }
            if (kon) *(float4*)&ks[(ch+1)&1][sk_t*64 + sk_m4] = rk;
        }
    }

    float* g = ws + WS_G + (size_t)(tsp*96 + b*6 + et)*4096;
    #pragma unroll
    for (int i = 0; i < 4; i++)
        *(float4*)&g[(mgr*4 + i)*64 + elg*4] =
            make_float4(acc[0][i], acc[1][i], acc[2][i], acc[3][i]);

    __syncthreads();
    if (xon) {
        redn[sx_t*64 + sx_e4+0] = s0; redn[sx_t*64 + sx_e4+1] = s1;
        redn[sx_t*64 + sx_e4+2] = s2; redn[sx_t*64 + sx_e4+3] = s3;
        reds[sx_t*64 + sx_e4+0] = q0; reds[sx_t*64 + sx_e4+1] = q1;
        reds[sx_t*64 + sx_e4+2] = q2; reds[sx_t*64 + sx_e4+3] = q3;
    }
    __syncthreads();
    if (tid < 64) {
        float s = 0.f, q = 0.f;
        #pragma unroll
        for (int rr = 0; rr < 12; rr++) { s += redn[rr*64 + tid]; q += reds[rr*64 + tid]; }
        const size_t o = (size_t)((tsp*16 + b)*6 + et)*64 + tid;
        ws[WS_PSUM + o] = s;
        ws[WS_PSS  + o] = q;
    }
}

// ============ k3f: fused — slabs+stats -> Cm in LDS -> out, denorm ============
// grid 192 = 16b x 3 e-tiles(128) x 4 t-quarters; 256 thr.
__global__ __launch_bounds__(256) void k3f(const float* __restrict__ aw,
        const float* __restrict__ ab, const float* __restrict__ ws,
        float* __restrict__ out)
{
    __shared__ float Cm[64*132];     // [m][e 128]
    __shared__ float EWm[64*68];     // [m][t' 64]
    __shared__ float ssc[128], ssh[128], smean[128], ssd[128], siaw[128], sabe[128];
    __shared__ float kss[64];
    const int tid = threadIdx.x;
    const int b   = blockIdx.x / 12;
    const int rr  = blockIdx.x % 12;
    const int eT  = rr / 4;
    const int tq  = rr % 4;
    const int e0  = eT * 128;
    const int et0 = eT * 2;

    if (tid < 128) {
        const int el = tid, e = e0 + el;
        const int et = et0 + (el >> 6), eli = el & 63;
        float s = 0.f, q = 0.f;
        #pragma unroll
        for (int tsp = 0; tsp < 4; tsp++) {
            const size_t o = (size_t)((tsp*16 + b)*6 + et)*64 + eli;
            s += ws[WS_PSUM + o];
            q += ws[WS_PSS  + o];
        }
        float mean = s * (1.0f/SEQ);
        float var  = q * (1.0f/SEQ) - mean*mean;
        float sd   = sqrtf(var + 1e-5f);
        if (e < ENC) {
            float a = aw[e], av = ab[e];
            float sc = a / sd;
            ssc[el] = sc; ssh[el] = av - mean*sc;
            smean[el] = mean; ssd[el] = sd;
            siaw[el] = 1.0f/(a + 1e-10f); sabe[el] = av;
        } else {
            ssc[el]=0.f; ssh[el]=0.f; smean[el]=0.f; ssd[el]=0.f; siaw[el]=0.f; sabe[el]=0.f;
        }
    }
    if (tid < 64) {
        float s = 0.f;
        #pragma unroll
        for (int p = 0; p < 17; p++) s += ws[WS_KSUMP + p*64 + tid];
        kss[tid] = s;
    }
    __syncthreads();

    const float* G = ws + WS_G;
    #pragma unroll
    for (int k = 0; k < 8; k++) {
        int slot = k*256 + tid;
        int m = slot >> 5, el4 = (slot & 31) * 4;
        int et = et0 + (el4 >> 6), eli4 = el4 & 63;
        size_t base = (size_t)(b*6 + et)*4096 + m*64 + eli4;
        float4 g0 = *(const float4*)&G[base];
        float4 g1 = *(const float4*)&G[base + (size_t) 96*4096];
        float4 g2 = *(const float4*)&G[base + (size_t)192*4096];
        float4 g3 = *(const float4*)&G[base + (size_t)288*4096];
        float km = kss[m];
        float4 c;
        c.x = ssc[el4+0]*(g0.x+g1.x+g2.x+g3.x) + ssh[el4+0]*km;
        c.y = ssc[el4+1]*(g0.y+g1.y+g2.y+g3.y) + ssh[el4+1]*km;
        c.z = ssc[el4+2]*(g0.z+g1.z+g2.z+g3.z) + ssh[el4+2]*km;
        c.w = ssc[el4+3]*(g0.w+g1.w+g2.w+g3.w) + ssh[el4+3]*km;
        *(float4*)&Cm[m*132 + el4] = c;
    }
    __syncthreads();

    const float* EWT = ws + WS_EWT;
    const float* evb = ws + WS_EVB;
    const int tx = tid & 31;
    const int ty = tid >> 5;
    for (int ti = 0; ti < 3; ti++) {
        const int tt0 = (tq*3 + ti) * 64;
        if (ti > 0) __syncthreads();
        #pragma unroll
        for (int k = 0; k < 4; k++) {
            int slot = k*256 + tid;
            int m = slot >> 4, t4 = (slot & 15)*4;
            int tp = tt0 + t4;
            float4 v;
            if (tp + 3 < PRED) v = *(const float4*)&EWT[(size_t)m*720 + tp];
            else {
                v = make_float4(0.f,0.f,0.f,0.f);
                if (tp   < PRED) v.x = EWT[(size_t)m*720 + tp];
                if (tp+1 < PRED) v.y = EWT[(size_t)m*720 + tp+1];
                if (tp+2 < PRED) v.z = EWT[(size_t)m*720 + tp+2];
            }
            *(float4*)&EWm[m*68 + t4] = v;
        }
        __syncthreads();

        float acc[8][4];
        #pragma unroll
        for (int i = 0; i < 8; i++)
            #pragma unroll
            for (int j = 0; j < 4; j++) acc[i][j] = 0.f;

        #pragma unroll 4
        for (int m = 0; m < 64; m++) {
            float4 c4 = *(const float4*)&Cm[m*132 + tx*4];
            float4 w0 = *(const float4*)&EWm[m*68 + ty*8];
            float4 w1 = *(const float4*)&EWm[m*68 + ty*8 + 4];
            acc[0][0]+=w0.x*c4.x; acc[0][1]+=w0.x*c4.y; acc[0][2]+=w0.x*c4.z; acc[0][3]+=w0.x*c4.w;
            acc[1][0]+=w0.y*c4.x; acc[1][1]+=w0.y*c4.y; acc[1][2]+=w0.y*c4.z; acc[1][3]+=w0.y*c4.w;
            acc[2][0]+=w0.z*c4.x; acc[2][1]+=w0.z*c4.y; acc[2][2]+=w0.z*c4.z; acc[2][3]+=w0.z*c4.w;
            acc[3][0]+=w0.w*c4.x; acc[3][1]+=w0.w*c4.y; acc[3][2]+=w0.w*c4.z; acc[3][3]+=w0.w*c4.w;
            acc[4][0]+=w1.x*c4.x; acc[4][1]+=w1.x*c4.y; acc[4][2]+=w1.x*c4.z; acc[4][3]+=w1.x*c4.w;
            acc[5][0]+=w1.y*c4.x; acc[5][1]+=w1.y*c4.y; acc[5][2]+=w1.y*c4.z; acc[5][3]+=w1.y*c4.w;
            acc[6][0]+=w1.z*c4.x; acc[6][1]+=w1.z*c4.y; acc[6][2]+=w1.z*c4.z; acc[6][3]+=w1.z*c4.w;
            acc[7][0]+=w1.w*c4.x; acc[7][1]+=w1.w*c4.y; acc[7][2]+=w1.w*c4.z; acc[7][3]+=w1.w*c4.w;
        }

        const int elb = tx*4;
        const int ebase = e0 + elb;
        #pragma unroll
        for (int i = 0; i < 8; i++) {
            int tp = tt0 + ty*8 + i;
            if (tp < PRED) {
                float ev = evb[tp];
                float* op = out + ((size_t)b*PRED + tp)*ENC;
                #pragma unroll
                for (int j = 0; j < 4; j++) {
                    int e = ebase + j;
                    if (e < ENC)
                        op[e] = (acc[i][j] + ev - sabe[elb+j]) * siaw[elb+j] * ssd[elb+j]
                                + smean[elb+j];
                }
            }
        }
    }
}

extern "C" void kernel_launch(void* const* d_in, const int* in_sizes, int n_in,
                              void* d_out, int out_size, void* d_ws, size_t ws_size,
                              hipStream_t stream)
{
    const float* x     = (const float*)d_in[0];
    const float* A     = (const float*)d_in[1];
    const float* Bv    = (const float*)d_in[2];
    const float* evalm = (const float*)d_in[3];
    const float* W     = (const float*)d_in[4];
    const float* bm    = (const float*)d_in[5];
    const float* aw    = (const float*)d_in[6];
    const float* ab    = (const float*)d_in[7];
    float* ws  = (float*)d_ws;
    float* out = (float*)d_out;

    prep2 <<<13, 256, 0, stream>>>(evalm, W, bm, A, Bv, ws);
    chains<<<16, 256, 0, stream>>>(ws);
    k2    <<<BATCH*6*4, 256, 0, stream>>>(x, ws);
    k3f   <<<192, 256, 0, stream>>>(aw, ab, ws, out);
}

// Round 11
// 174.403 us; speedup vs baseline: 1.0731x; 1.0219x over previous
//
#include <hip/hip_runtime.h>
#include <math.h>

#define BATCH 16
#define SEQ   720
#define ENC   321
#define NORD  64
#define PRED  720
#define NPAIR (BATCH*ENC)    // 5136

// ---- ws layout (float offsets) ----
#define WS_KT    0                         // 720x64: Kt[t][m] = (A^(719-t) B)[m]
#define WS_EWT   (WS_KT + PRED*NORD)       // 64x720: EW^T [m][t']
#define WS_EVB   (WS_EWT + NORD*PRED)      // 720
#define WS_A16   (WS_EVB + PRED)           // 64x64
#define WS_KSUMP (WS_A16 + 4096)           // 17x64 Ksum partials (16 chains + 1 prepK)
#define WS_G     (WS_KSUMP + 17*64)        // 4 tsp x 96 x 4096, m-major [m][el]
#define WS_PSUM  (WS_G + 4*96*4096)
#define WS_PSS   (WS_PSUM + 4*16*6*64)

// ============ prepK (1 block, 256 thr): rows 0..15 + 4 squarings -> A^16 ============
// LDS-issue model: each squaring costs 1024 ds_read_b128/CU (~5.1us); 4 squarings ~= 25us.
__global__ __launch_bounds__(256, 1) void prepK(const float* __restrict__ A,
        const float* __restrict__ Bv, float* __restrict__ ws)
{
    __shared__ float Kl[16*64];      // K rows 0..15
    __shared__ float Ap[64*68];      // A^m
    __shared__ float ApT[64*68];     // (A^m)^T
    __shared__ float red[4*64];
    const int tid  = threadIdx.x;
    const int lane = tid & 63;
    const int wv   = tid >> 6;       // 0..3
    float* Kt = ws + WS_KT;
    for (int idx = tid; idx < 4096; idx += 256) {
        int n = idx >> 6, m = idx & 63;
        float v = A[idx];
        Ap[n*68+m] = v; ApT[m*68+n] = v;
    }
    float ksml = 0.f;                // partial of Ksum[lane], rows 0..15
    if (tid < 64) {
        float bv = Bv[tid];
        Kl[tid] = bv;
        Kt[(size_t)719*64 + tid] = bv;
        ksml += bv;                  // row 0
    }
    __syncthreads();
    float ar[64];                    // row `lane` of A^m (stays in VGPRs at 256 thr)
    #pragma unroll
    for (int k = 0; k < 16; k++) {
        float4 v = *(const float4*)&Ap[lane*68 + 4*k];
        ar[4*k]=v.x; ar[4*k+1]=v.y; ar[4*k+2]=v.z; ar[4*k+3]=v.w;
    }
    for (int mm = 1; mm <= 8; mm <<= 1) {
        // expand rows mm..2mm-1:  K[j2] = A^mm @ K[j2-mm]   (rows 1..15 total)
        for (int j2 = mm + wv; j2 < 2*mm; j2 += 4) {
            const float* src = &Kl[(j2 - mm)*64];
            float acc = 0.f;
            #pragma unroll
            for (int k = 0; k < 16; k++) {
                float4 s = *(const float4*)&src[4*k];    // wave-uniform broadcast
                acc += ar[4*k]*s.x + ar[4*k+1]*s.y + ar[4*k+2]*s.z + ar[4*k+3]*s.w;
            }
            Kl[j2*64 + lane] = acc;
            Kt[(size_t)(719 - j2)*64 + lane] = acc;
            ksml += acc;
        }
        // square: A^(2mm) = A^mm @ A^mm ; wave handles 16 columns
        float nacc[16];
        #pragma unroll
        for (int q = 0; q < 16; q++) {
            int c = wv*16 + q;
            const float* src = &ApT[c*68];
            float acc = 0.f;
            #pragma unroll
            for (int k = 0; k < 16; k++) {
                float4 s = *(const float4*)&src[4*k];
                acc += ar[4*k]*s.x + ar[4*k+1]*s.y + ar[4*k+2]*s.z + ar[4*k+3]*s.w;
            }
            nacc[q] = acc;
        }
        __syncthreads();
        #pragma unroll
        for (int q = 0; q < 16; q++) {
            int c = wv*16 + q;
            Ap[lane*68 + c]  = nacc[q];
            ApT[c*68 + lane] = nacc[q];
        }
        __syncthreads();
        #pragma unroll
        for (int k = 0; k < 16; k++) {
            float4 v = *(const float4*)&Ap[lane*68 + 4*k];
            ar[4*k]=v.x; ar[4*k+1]=v.y; ar[4*k+2]=v.z; ar[4*k+3]=v.w;
        }
        mm = mm; // (loop increment shifts mm)
    }
    // Ap holds A^16
    for (int idx = tid; idx < 4096; idx += 256)
        ws[WS_A16 + idx] = Ap[(idx>>6)*68 + (idx&63)];
    __syncthreads();
    red[wv*64 + lane] = ksml;
    __syncthreads();
    if (tid < 64)
        ws[WS_KSUMP + 16*64 + tid] = red[tid] + red[64+tid] + red[128+tid] + red[192+tid];
}

// ============ chainsEW: [bid<16] chain r: K[r+16q]=A^16 K[..] (44 steps, 1 wave/CU)
//              [bid>=16] EW^T = (eval@W)^T + evb (12 blocks) ============
__global__ __launch_bounds__(256, 1) void chainsEW(const float* __restrict__ evalm,
        const float* __restrict__ W, const float* __restrict__ bm,
        float* __restrict__ ws)
{
    __shared__ float dsm[8224];      // EW: smW(4160)+Et(3904); chains: sv(64)
    const int tid  = threadIdx.x;
    const int lane = tid & 63;
    const int wv   = tid >> 6;
    if (blockIdx.x < 16) {
        if (tid >= 64) return;       // 1 wave per chain block (no syncthreads below)
        float* sv = dsm;
        const int r = blockIdx.x;    // chain 0..15
        const float* A16 = ws + WS_A16;
        float* Kt = ws + WS_KT;
        float ar16[64];
        #pragma unroll
        for (int k = 0; k < 16; k++) {
            float4 v = *(const float4*)&A16[lane*64 + 4*k];
            ar16[4*k]=v.x; ar16[4*k+1]=v.y; ar16[4*k+2]=v.z; ar16[4*k+3]=v.w;
        }
        float ksml = 0.f;
        sv[lane] = Kt[(size_t)(719 - r)*64 + lane];   // seed K[r]
        for (int j = r + 16; j <= 719; j += 16) {     // exactly 44 steps
            float acc = 0.f;
            #pragma unroll
            for (int k = 0; k < 16; k++) {
                float4 v = *(const float4*)&sv[4*k];
                acc += ar16[4*k]*v.x + ar16[4*k+1]*v.y + ar16[4*k+2]*v.z + ar16[4*k+3]*v.w;
            }
            sv[lane] = acc;                           // same-wave DS ordering
            Kt[(size_t)(719 - j)*64 + lane] = acc;
            ksml += acc;                              // rows 16..719, each once
        }
        ws[WS_KSUMP + r*64 + lane] = ksml;
    } else {
        float* smW = dsm;            // [n][m] pad 65
        float* Et  = dsm + 4160;     // [m][row] pad 61
        const int r = blockIdx.x - 16;
        for (int idx = tid; idx < 4096; idx += 256)
            smW[(idx>>6)*65 + (idx&63)] = W[idx];
        __syncthreads();
        float bv = bm[lane];
        #pragma unroll
        for (int k = 0; k < 15; k++) {
            int row = wv + k*4;              // rows 0..59
            int tp = r*60 + row;
            const float* ev = evalm + (size_t)tp*64;
            float acc = 0.f;
            #pragma unroll
            for (int kk = 0; kk < 16; kk++) {
                float4 e4 = *(const float4*)&ev[4*kk];
                acc += e4.x*smW[(4*kk+0)*65+lane] + e4.y*smW[(4*kk+1)*65+lane]
                     + e4.z*smW[(4*kk+2)*65+lane] + e4.w*smW[(4*kk+3)*65+lane];
            }
            Et[lane*61 + row] = acc;
            float pv = ev[lane] * bv;
            #pragma unroll
            for (int o = 32; o > 0; o >>= 1) pv += __shfl_down(pv, o);
            if (lane == 0) ws[WS_EVB + tp] = pv;
        }
        __syncthreads();
        for (int idx = tid; idx < 4096; idx += 256) {
            int m = idx >> 6, row = idx & 63;
            if (row < 60)
                ws[WS_EWT + (size_t)m*720 + r*60 + row] = Et[m*61 + row];
        }
    }
}

// ============ k2: G[m][el] slabs (m-major) + stats partials (unchanged, R10) ============
__device__ inline float4 ldx(const float* __restrict__ x, int b, int t, int e4)
{
    float4 r = make_float4(0.f,0.f,0.f,0.f);
    const float* p = x + ((size_t)b*SEQ + t)*ENC;
    if (e4 + 3 < ENC) r = *(const float4*)&p[e4];
    else {
        if (e4   < ENC) r.x = p[e4];
        if (e4+1 < ENC) r.y = p[e4+1];
        if (e4+2 < ENC) r.z = p[e4+2];
    }
    return r;
}

__global__ __launch_bounds__(256) void k2(const float* __restrict__ x,
        float* __restrict__ ws)
{
    __shared__ float xt[2][12*64];
    __shared__ float ks[2][12*64];
    __shared__ float redn[12*64];
    __shared__ float reds[12*64];
    const int tid = threadIdx.x;
    const int bid = blockIdx.x;
    const int b = bid / 24, rem = bid % 24;
    const int et = rem / 4, tsp = rem % 4;
    const int e0 = et*64, t0 = tsp*180;

    const bool xon = tid < 192;
    const bool kon = tid >= 64;
    const int sx_t  = tid >> 4;
    const int sx_e4 = (tid & 15) * 4;
    const int sk    = tid - 64;
    const int sk_t  = sk >> 4;
    const int sk_m4 = (sk & 15) * 4;

    const float* Kt = ws + WS_KT;
    float s0=0,s1=0,s2=0,s3=0, q0=0,q1=0,q2=0,q3=0;
    float4 rx = make_float4(0,0,0,0), rk = make_float4(0,0,0,0);

    if (xon) rx = ldx(x, b, t0 + sx_t, e0 + sx_e4);
    if (kon) rk = *(const float4*)&Kt[(size_t)(t0 + sk_t)*64 + sk_m4];
    if (xon) {
        *(float4*)&xt[0][sx_t*64 + sx_e4] = rx;
        s0+=rx.x; s1+=rx.y; s2+=rx.z; s3+=rx.w;
        q0+=rx.x*rx.x; q1+=rx.y*rx.y; q2+=rx.z*rx.z; q3+=rx.w*rx.w;
    }
    if (kon) *(float4*)&ks[0][sk_t*64 + sk_m4] = rk;

    const int lane = tid & 63, wv = tid >> 6;
    const int elg = lane & 15;            // el = elg*4 + j
    const int mgr = wv*4 + (lane >> 4);   // m  = mgr*4 + i
    float acc[4][4];
    #pragma unroll
    for (int j = 0; j < 4; j++)
        #pragma unroll
        for (int i = 0; i < 4; i++) acc[j][i] = 0.f;

    for (int ch = 0; ch < 15; ch++) {
        if (ch + 1 < 15) {
            if (xon) rx = ldx(x, b, t0 + (ch+1)*12 + sx_t, e0 + sx_e4);
            if (kon) rk = *(const float4*)&Kt[(size_t)(t0 + (ch+1)*12 + sk_t)*64 + sk_m4];
        }
        __syncthreads();
        const float* xb = xt[ch & 1];
        const float* kb = ks[ch & 1];
        #pragma unroll
        for (int tt = 0; tt < 12; tt++) {
            float4 f  = *(const float4*)&xb[tt*64 + elg*4];
            float4 kv = *(const float4*)&kb[tt*64 + mgr*4];
            acc[0][0]+=f.x*kv.x; acc[0][1]+=f.x*kv.y; acc[0][2]+=f.x*kv.z; acc[0][3]+=f.x*kv.w;
            acc[1][0]+=f.y*kv.x; acc[1][1]+=f.y*kv.y; acc[1][2]+=f.y*kv.z; acc[1][3]+=f.y*kv.w;
            acc[2][0]+=f.z*kv.x; acc[2][1]+=f.z*kv.y; acc[2][2]+=f.z*kv.z; acc[2][3]+=f.z*kv.w;
            acc[3][0]+=f.w*kv.x; acc[3][1]+=f.w*kv.y; acc[3][2]+=f.w*kv.z; acc[3][3]+=f.w*kv.w;
        }
        if (ch + 1 < 15) {
            if (xon) {
                *(float4*)&xt[(ch+1)&1][sx_t*64 + sx_e4] = rx;
                s0+=rx.x; s1+=rx.y; s2+=rx.z; s3+=rx.w;
                q0+=rx.x*rx.x; q1+=rx.y*rx.y; q2+=rx.z*rx.z; q3+=rx.w*rx.w;
            }
            if (kon) *(float4*)&ks[(ch+1)&1][sk_t*64 + sk_m4] = rk;
        }
    }

    float* g = ws + WS_G + (size_t)(tsp*96 + b*6 + et)*4096;
    #pragma unroll
    for (int i = 0; i < 4; i++)
        *(float4*)&g[(mgr*4 + i)*64 + elg*4] =
            make_float4(acc[0][i], acc[1][i], acc[2][i], acc[3][i]);

    __syncthreads();
    if (xon) {
        redn[sx_t*64 + sx_e4+0] = s0; redn[sx_t*64 + sx_e4+1] = s1;
        redn[sx_t*64 + sx_e4+2] = s2; redn[sx_t*64 + sx_e4+3] = s3;
        reds[sx_t*64 + sx_e4+0] = q0; reds[sx_t*64 + sx_e4+1] = q1;
        reds[sx_t*64 + sx_e4+2] = q2; reds[sx_t*64 + sx_e4+3] = q3;
    }
    __syncthreads();
    if (tid < 64) {
        float s = 0.f, q = 0.f;
        #pragma unroll
        for (int rr = 0; rr < 12; rr++) { s += redn[rr*64 + tid]; q += reds[rr*64 + tid]; }
        const size_t o = (size_t)((tsp*16 + b)*6 + et)*64 + tid;
        ws[WS_PSUM + o] = s;
        ws[WS_PSS  + o] = q;
    }
}

// ============ k3f: fused — slabs+stats -> Cm in LDS -> out, denorm (unchanged, R10) ============
__global__ __launch_bounds__(256) void k3f(const float* __restrict__ aw,
        const float* __restrict__ ab, const float* __restrict__ ws,
        float* __restrict__ out)
{
    __shared__ float Cm[64*132];     // [m][e 128]
    __shared__ float EWm[64*68];     // [m][t' 64]
    __shared__ float ssc[128], ssh[128], smean[128], ssd[128], siaw[128], sabe[128];
    __shared__ float kss[64];
    const int tid = threadIdx.x;
    const int b   = blockIdx.x / 12;
    const int rr  = blockIdx.x % 12;
    const int eT  = rr / 4;
    const int tq  = rr % 4;
    const int e0  = eT * 128;
    const int et0 = eT * 2;

    if (tid < 128) {
        const int el = tid, e = e0 + el;
        const int et = et0 + (el >> 6), eli = el & 63;
        float s = 0.f, q = 0.f;
        #pragma unroll
        for (int tsp = 0; tsp < 4; tsp++) {
            const size_t o = (size_t)((tsp*16 + b)*6 + et)*64 + eli;
            s += ws[WS_PSUM + o];
            q += ws[WS_PSS  + o];
        }
        float mean = s * (1.0f/SEQ);
        float var  = q * (1.0f/SEQ) - mean*mean;
        float sd   = sqrtf(var + 1e-5f);
        if (e < ENC) {
            float a = aw[e], av = ab[e];
            float sc = a / sd;
            ssc[el] = sc; ssh[el] = av - mean*sc;
            smean[el] = mean; ssd[el] = sd;
            siaw[el] = 1.0f/(a + 1e-10f); sabe[el] = av;
        } else {
            ssc[el]=0.f; ssh[el]=0.f; smean[el]=0.f; ssd[el]=0.f; siaw[el]=0.f; sabe[el]=0.f;
        }
    }
    if (tid < 64) {
        float s = 0.f;
        #pragma unroll
        for (int p = 0; p < 17; p++) s += ws[WS_KSUMP + p*64 + tid];
        kss[tid] = s;
    }
    __syncthreads();

    const float* G = ws + WS_G;
    #pragma unroll
    for (int k = 0; k < 8; k++) {
        int slot = k*256 + tid;
        int m = slot >> 5, el4 = (slot & 31) * 4;
        int et = et0 + (el4 >> 6), eli4 = el4 & 63;
        size_t base = (size_t)(b*6 + et)*4096 + m*64 + eli4;
        float4 g0 = *(const float4*)&G[base];
        float4 g1 = *(const float4*)&G[base + (size_t) 96*4096];
        float4 g2 = *(const float4*)&G[base + (size_t)192*4096];
        float4 g3 = *(const float4*)&G[base + (size_t)288*4096];
        float km = kss[m];
        float4 c;
        c.x = ssc[el4+0]*(g0.x+g1.x+g2.x+g3.x) + ssh[el4+0]*km;
        c.y = ssc[el4+1]*(g0.y+g1.y+g2.y+g3.y) + ssh[el4+1]*km;
        c.z = ssc[el4+2]*(g0.z+g1.z+g2.z+g3.z) + ssh[el4+2]*km;
        c.w = ssc[el4+3]*(g0.w+g1.w+g2.w+g3.w) + ssh[el4+3]*km;
        *(float4*)&Cm[m*132 + el4] = c;
    }
    __syncthreads();

    const float* EWT = ws + WS_EWT;
    const float* evb = ws + WS_EVB;
    const int tx = tid & 31;
    const int ty = tid >> 5;
    for (int ti = 0; ti < 3; ti++) {
        const int tt0 = (tq*3 + ti) * 64;
        if (ti > 0) __syncthreads();
        #pragma unroll
        for (int k = 0; k < 4; k++) {
            int slot = k*256 + tid;
            int m = slot >> 4, t4 = (slot & 15)*4;
            int tp = tt0 + t4;
            float4 v;
            if (tp + 3 < PRED) v = *(const float4*)&EWT[(size_t)m*720 + tp];
            else {
                v = make_float4(0.f,0.f,0.f,0.f);
                if (tp   < PRED) v.x = EWT[(size_t)m*720 + tp];
                if (tp+1 < PRED) v.y = EWT[(size_t)m*720 + tp+1];
                if (tp+2 < PRED) v.z = EWT[(size_t)m*720 + tp+2];
            }
            *(float4*)&EWm[m*68 + t4] = v;
        }
        __syncthreads();

        float acc[8][4];
        #pragma unroll
        for (int i = 0; i < 8; i++)
            #pragma unroll
            for (int j = 0; j < 4; j++) acc[i][j] = 0.f;

        #pragma unroll 4
        for (int m = 0; m < 64; m++) {
            float4 c4 = *(const float4*)&Cm[m*132 + tx*4];
            float4 w0 = *(const float4*)&EWm[m*68 + ty*8];
            float4 w1 = *(const float4*)&EWm[m*68 + ty*8 + 4];
            acc[0][0]+=w0.x*c4.x; acc[0][1]+=w0.x*c4.y; acc[0][2]+=w0.x*c4.z; acc[0][3]+=w0.x*c4.w;
            acc[1][0]+=w0.y*c4.x; acc[1][1]+=w0.y*c4.y; acc[1][2]+=w0.y*c4.z; acc[1][3]+=w0.y*c4.w;
            acc[2][0]+=w0.z*c4.x; acc[2][1]+=w0.z*c4.y; acc[2][2]+=w0.z*c4.z; acc[2][3]+=w0.z*c4.w;
            acc[3][0]+=w0.w*c4.x; acc[3][1]+=w0.w*c4.y; acc[3][2]+=w0.w*c4.z; acc[3][3]+=w0.w*c4.w;
            acc[4][0]+=w1.x*c4.x; acc[4][1]+=w1.x*c4.y; acc[4][2]+=w1.x*c4.z; acc[4][3]+=w1.x*c4.w;
            acc[5][0]+=w1.y*c4.x; acc[5][1]+=w1.y*c4.y; acc[5][2]+=w1.y*c4.z; acc[5][3]+=w1.y*c4.w;
            acc[6][0]+=w1.z*c4.x; acc[6][1]+=w1.z*c4.y; acc[6][2]+=w1.z*c4.z; acc[6][3]+=w1.z*c4.w;
            acc[7][0]+=w1.w*c4.x; acc[7][1]+=w1.w*c4.y; acc[7][2]+=w1.w*c4.z; acc[7][3]+=w1.w*c4.w;
        }

        const int elb = tx*4;
        const int ebase = e0 + elb;
        #pragma unroll
        for (int i = 0; i < 8; i++) {
            int tp = tt0 + ty*8 + i;
            if (tp < PRED) {
                float ev = evb[tp];
                float* op = out + ((size_t)b*PRED + tp)*ENC;
                #pragma unroll
                for (int j = 0; j < 4; j++) {
                    int e = ebase + j;
                    if (e < ENC)
                        op[e] = (acc[i][j] + ev - sabe[elb+j]) * siaw[elb+j] * ssd[elb+j]
                                + smean[elb+j];
                }
            }
        }
    }
}

extern "C" void kernel_launch(void* const* d_in, const int* in_sizes, int n_in,
                              void* d_out, int out_size, void* d_ws, size_t ws_size,
                              hipStream_t stream)
{
    const float* x     = (const float*)d_in[0];
    const float* A     = (const float*)d_in[1];
    const float* Bv    = (const float*)d_in[2];
    const float* evalm = (const float*)d_in[3];
    const float* W     = (const float*)d_in[4];
    const float* bm    = (const float*)d_in[5];
    const float* aw    = (const float*)d_in[6];
    const float* ab    = (const float*)d_in[7];
    float* ws  = (float*)d_ws;
    float* out = (float*)d_out;

    prepK   <<<1, 256, 0, stream>>>(A, Bv, ws);
    chainsEW<<<28, 256, 0, stream>>>(evalm, W, bm, ws);
    k2      <<<BATCH*6*4, 256, 0, stream>>>(x, ws);
    k3f     <<<192, 256, 0, stream>>>(aw, ab, ws, out);
}

// Round 12
// 158.301 us; speedup vs baseline: 1.1823x; 1.1017x over previous
//
#include <hip/hip_runtime.h>
#include <math.h>

#define BATCH 16
#define SEQ   720
#define ENC   321
#define NORD  64
#define PRED  720
#define NPAIR (BATCH*ENC)    // 5136

// ---- ws layout (float offsets) ----
#define WS_KT    0                         // 720x64: Kt[t][m] = (A^(719-t) B)[m]
#define WS_EWT   (WS_KT + PRED*NORD)       // 64x720: EW^T [m][t']
#define WS_EVB   (WS_EWT + NORD*PRED)      // 720
#define WS_A16   (WS_EVB + PRED)           // 64x64 row-major
#define WS_KSUMP (WS_A16 + 4096)           // 17x64 Ksum partials (16 chains + 1 prep)
#define WS_G     (WS_KSUMP + 17*64)        // 4 tsp x 96 x 4096, m-major [m][el]
#define WS_PSUM  (WS_G + 4*96*4096)
#define WS_PSS   (WS_PSUM + 4*16*6*64)

// ============ prep: NO squarings (R11 post-mortem: each 1-CU squaring = hard ~5us
// ds_read_b128-issue floor). A^16 built as 64 independent depth-16 column chains
// col_j(A^16) = A^16 e_j across 16 blocks; K rows 0..15 = depth-15 chain from B. ============
__global__ __launch_bounds__(256, 1) void prep(const float* __restrict__ A,
        const float* __restrict__ Bv, float* __restrict__ ws)
{
    __shared__ float sv[4][64];
    const int tid  = threadIdx.x;
    const int lane = tid & 63;
    const int wv   = tid >> 6;
    if (blockIdx.x < 16) {
        // ---- A^16 columns: wave wv of block bid owns column j ----
        float ar[64];                        // row `lane` of A
        #pragma unroll
        for (int k = 0; k < 16; k++) {
            float4 v = *(const float4*)&A[lane*64 + 4*k];
            ar[4*k]=v.x; ar[4*k+1]=v.y; ar[4*k+2]=v.z; ar[4*k+3]=v.w;
        }
        const int j = blockIdx.x*4 + wv;     // column 0..63
        sv[wv][lane] = (lane == j) ? 1.f : 0.f;
        for (int s = 0; s < 16; s++) {       // v <- A v, 16 times
            float acc = 0.f;
            #pragma unroll
            for (int k = 0; k < 16; k++) {
                float4 v = *(const float4*)&sv[wv][4*k];
                acc += ar[4*k]*v.x + ar[4*k+1]*v.y + ar[4*k+2]*v.z + ar[4*k+3]*v.w;
            }
            sv[wv][lane] = acc;              // same-wave DS ordering
        }
        ws[WS_A16 + lane*64 + j] = sv[wv][lane];   // element (lane, j), row-major
    } else {
        // ---- K rows 0..15 (one wave): K[0]=B, K[j]=A K[j-1] ----
        if (tid >= 64) return;
        float ar[64];
        #pragma unroll
        for (int k = 0; k < 16; k++) {
            float4 v = *(const float4*)&A[lane*64 + 4*k];
            ar[4*k]=v.x; ar[4*k+1]=v.y; ar[4*k+2]=v.z; ar[4*k+3]=v.w;
        }
        float* Kt = ws + WS_KT;
        float bv = Bv[lane];
        sv[0][lane] = bv;
        Kt[(size_t)719*64 + lane] = bv;
        float ksml = bv;
        for (int j = 1; j <= 15; j++) {
            float acc = 0.f;
            #pragma unroll
            for (int k = 0; k < 16; k++) {
                float4 v = *(const float4*)&sv[0][4*k];
                acc += ar[4*k]*v.x + ar[4*k+1]*v.y + ar[4*k+2]*v.z + ar[4*k+3]*v.w;
            }
            sv[0][lane] = acc;
            Kt[(size_t)(719 - j)*64 + lane] = acc;
            ksml += acc;
        }
        ws[WS_KSUMP + 16*64 + lane] = ksml;  // partial: rows 0..15
    }
}

// ============ chainsEW: [bid<16] chain r: K[r+16q]=A^16 K[..] (44 steps)
//              [bid>=16] EW^T = (eval@W)^T + evb (12 blocks) — unchanged (R11) ============
__global__ __launch_bounds__(256, 1) void chainsEW(const float* __restrict__ evalm,
        const float* __restrict__ W, const float* __restrict__ bm,
        float* __restrict__ ws)
{
    __shared__ float dsm[8224];
    const int tid  = threadIdx.x;
    const int lane = tid & 63;
    const int wv   = tid >> 6;
    if (blockIdx.x < 16) {
        if (tid >= 64) return;       // 1 wave per chain block
        float* sv = dsm;
        const int r = blockIdx.x;    // chain 0..15
        const float* A16 = ws + WS_A16;
        float* Kt = ws + WS_KT;
        float ar16[64];
        #pragma unroll
        for (int k = 0; k < 16; k++) {
            float4 v = *(const float4*)&A16[lane*64 + 4*k];
            ar16[4*k]=v.x; ar16[4*k+1]=v.y; ar16[4*k+2]=v.z; ar16[4*k+3]=v.w;
        }
        float ksml = 0.f;
        sv[lane] = Kt[(size_t)(719 - r)*64 + lane];   // seed K[r]
        for (int j = r + 16; j <= 719; j += 16) {     // 44 steps
            float acc = 0.f;
            #pragma unroll
            for (int k = 0; k < 16; k++) {
                float4 v = *(const float4*)&sv[4*k];
                acc += ar16[4*k]*v.x + ar16[4*k+1]*v.y + ar16[4*k+2]*v.z + ar16[4*k+3]*v.w;
            }
            sv[lane] = acc;                           // same-wave DS ordering
            Kt[(size_t)(719 - j)*64 + lane] = acc;
            ksml += acc;
        }
        ws[WS_KSUMP + r*64 + lane] = ksml;
    } else {
        float* smW = dsm;            // [n][m] pad 65
        float* Et  = dsm + 4160;     // [m][row] pad 61
        const int r = blockIdx.x - 16;
        for (int idx = tid; idx < 4096; idx += 256)
            smW[(idx>>6)*65 + (idx&63)] = W[idx];
        __syncthreads();
        float bv = bm[lane];
        #pragma unroll
        for (int k = 0; k < 15; k++) {
            int row = wv + k*4;              // rows 0..59
            int tp = r*60 + row;
            const float* ev = evalm + (size_t)tp*64;
            float acc = 0.f;
            #pragma unroll
            for (int kk = 0; kk < 16; kk++) {
                float4 e4 = *(const float4*)&ev[4*kk];
                acc += e4.x*smW[(4*kk+0)*65+lane] + e4.y*smW[(4*kk+1)*65+lane]
                     + e4.z*smW[(4*kk+2)*65+lane] + e4.w*smW[(4*kk+3)*65+lane];
            }
            Et[lane*61 + row] = acc;
            float pv = ev[lane] * bv;
            #pragma unroll
            for (int o = 32; o > 0; o >>= 1) pv += __shfl_down(pv, o);
            if (lane == 0) ws[WS_EVB + tp] = pv;
        }
        __syncthreads();
        for (int idx = tid; idx < 4096; idx += 256) {
            int m = idx >> 6, row = idx & 63;
            if (row < 60)
                ws[WS_EWT + (size_t)m*720 + r*60 + row] = Et[m*61 + row];
        }
    }
}

// ============ k2: G[m][el] slabs (m-major) + stats partials (unchanged, R11) ============
__device__ inline float4 ldx(const float* __restrict__ x, int b, int t, int e4)
{
    float4 r = make_float4(0.f,0.f,0.f,0.f);
    const float* p = x + ((size_t)b*SEQ + t)*ENC;
    if (e4 + 3 < ENC) r = *(const float4*)&p[e4];
    else {
        if (e4   < ENC) r.x = p[e4];
        if (e4+1 < ENC) r.y = p[e4+1];
        if (e4+2 < ENC) r.z = p[e4+2];
    }
    return r;
}

__global__ __launch_bounds__(256) void k2(const float* __restrict__ x,
        float* __restrict__ ws)
{
    __shared__ float xt[2][12*64];
    __shared__ float ks[2][12*64];
    __shared__ float redn[12*64];
    __shared__ float reds[12*64];
    const int tid = threadIdx.x;
    const int bid = blockIdx.x;
    const int b = bid / 24, rem = bid % 24;
    const int et = rem / 4, tsp = rem % 4;
    const int e0 = et*64, t0 = tsp*180;

    const bool xon = tid < 192;
    const bool kon = tid >= 64;
    const int sx_t  = tid >> 4;
    const int sx_e4 = (tid & 15) * 4;
    const int sk    = tid - 64;
    const int sk_t  = sk >> 4;
    const int sk_m4 = (sk & 15) * 4;

    const float* Kt = ws + WS_KT;
    float s0=0,s1=0,s2=0,s3=0, q0=0,q1=0,q2=0,q3=0;
    float4 rx = make_float4(0,0,0,0), rk = make_float4(0,0,0,0);

    if (xon) rx = ldx(x, b, t0 + sx_t, e0 + sx_e4);
    if (kon) rk = *(const float4*)&Kt[(size_t)(t0 + sk_t)*64 + sk_m4];
    if (xon) {
        *(float4*)&xt[0][sx_t*64 + sx_e4] = rx;
        s0+=rx.x; s1+=rx.y; s2+=rx.z; s3+=rx.w;
        q0+=rx.x*rx.x; q1+=rx.y*rx.y; q2+=rx.z*rx.z; q3+=rx.w*rx.w;
    }
    if (kon) *(float4*)&ks[0][sk_t*64 + sk_m4] = rk;

    const int lane = tid & 63, wv = tid >> 6;
    const int elg = lane & 15;            // el = elg*4 + j
    const int mgr = wv*4 + (lane >> 4);   // m  = mgr*4 + i
    float acc[4][4];
    #pragma unroll
    for (int j = 0; j < 4; j++)
        #pragma unroll
        for (int i = 0; i < 4; i++) acc[j][i] = 0.f;

    for (int ch = 0; ch < 15; ch++) {
        if (ch + 1 < 15) {
            if (xon) rx = ldx(x, b, t0 + (ch+1)*12 + sx_t, e0 + sx_e4);
            if (kon) rk = *(const float4*)&Kt[(size_t)(t0 + (ch+1)*12 + sk_t)*64 + sk_m4];
        }
        __syncthreads();
        const float* xb = xt[ch & 1];
        const float* kb = ks[ch & 1];
        #pragma unroll
        for (int tt = 0; tt < 12; tt++) {
            float4 f  = *(const float4*)&xb[tt*64 + elg*4];
            float4 kv = *(const float4*)&kb[tt*64 + mgr*4];
            acc[0][0]+=f.x*kv.x; acc[0][1]+=f.x*kv.y; acc[0][2]+=f.x*kv.z; acc[0][3]+=f.x*kv.w;
            acc[1][0]+=f.y*kv.x; acc[1][1]+=f.y*kv.y; acc[1][2]+=f.y*kv.z; acc[1][3]+=f.y*kv.w;
            acc[2][0]+=f.z*kv.x; acc[2][1]+=f.z*kv.y; acc[2][2]+=f.z*kv.z; acc[2][3]+=f.z*kv.w;
            acc[3][0]+=f.w*kv.x; acc[3][1]+=f.w*kv.y; acc[3][2]+=f.w*kv.z; acc[3][3]+=f.w*kv.w;
        }
        if (ch + 1 < 15) {
            if (xon) {
                *(float4*)&xt[(ch+1)&1][sx_t*64 + sx_e4] = rx;
                s0+=rx.x; s1+=rx.y; s2+=rx.z; s3+=rx.w;
                q0+=rx.x*rx.x; q1+=rx.y*rx.y; q2+=rx.z*rx.z; q3+=rx.w*rx.w;
            }
            if (kon) *(float4*)&ks[(ch+1)&1][sk_t*64 + sk_m4] = rk;
        }
    }

    float* g = ws + WS_G + (size_t)(tsp*96 + b*6 + et)*4096;
    #pragma unroll
    for (int i = 0; i < 4; i++)
        *(float4*)&g[(mgr*4 + i)*64 + elg*4] =
            make_float4(acc[0][i], acc[1][i], acc[2][i], acc[3][i]);

    __syncthreads();
    if (xon) {
        redn[sx_t*64 + sx_e4+0] = s0; redn[sx_t*64 + sx_e4+1] = s1;
        redn[sx_t*64 + sx_e4+2] = s2; redn[sx_t*64 + sx_e4+3] = s3;
        reds[sx_t*64 + sx_e4+0] = q0; reds[sx_t*64 + sx_e4+1] = q1;
        reds[sx_t*64 + sx_e4+2] = q2; reds[sx_t*64 + sx_e4+3] = q3;
    }
    __syncthreads();
    if (tid < 64) {
        float s = 0.f, q = 0.f;
        #pragma unroll
        for (int rr = 0; rr < 12; rr++) { s += redn[rr*64 + tid]; q += reds[rr*64 + tid]; }
        const size_t o = (size_t)((tsp*16 + b)*6 + et)*64 + tid;
        ws[WS_PSUM + o] = s;
        ws[WS_PSS  + o] = q;
    }
}

// ============ k3f: fused — slabs+stats -> Cm in LDS -> out, denorm (unchanged, R11) ============
__global__ __launch_bounds__(256) void k3f(const float* __restrict__ aw,
        const float* __restrict__ ab, const float* __restrict__ ws,
        float* __restrict__ out)
{
    __shared__ float Cm[64*132];     // [m][e 128]
    __shared__ float EWm[64*68];     // [m][t' 64]
    __shared__ float ssc[128], ssh[128], smean[128], ssd[128], siaw[128], sabe[128];
    __shared__ float kss[64];
    const int tid = threadIdx.x;
    const int b   = blockIdx.x / 12;
    const int rr  = blockIdx.x % 12;
    const int eT  = rr / 4;
    const int tq  = rr % 4;
    const int e0  = eT * 128;
    const int et0 = eT * 2;

    if (tid < 128) {
        const int el = tid, e = e0 + el;
        const int et = et0 + (el >> 6), eli = el & 63;
        float s = 0.f, q = 0.f;
        #pragma unroll
        for (int tsp = 0; tsp < 4; tsp++) {
            const size_t o = (size_t)((tsp*16 + b)*6 + et)*64 + eli;
            s += ws[WS_PSUM + o];
            q += ws[WS_PSS  + o];
        }
        float mean = s * (1.0f/SEQ);
        float var  = q * (1.0f/SEQ) - mean*mean;
        float sd   = sqrtf(var + 1e-5f);
        if (e < ENC) {
            float a = aw[e], av = ab[e];
            float sc = a / sd;
            ssc[el] = sc; ssh[el] = av - mean*sc;
            smean[el] = mean; ssd[el] = sd;
            siaw[el] = 1.0f/(a + 1e-10f); sabe[el] = av;
        } else {
            ssc[el]=0.f; ssh[el]=0.f; smean[el]=0.f; ssd[el]=0.f; siaw[el]=0.f; sabe[el]=0.f;
        }
    }
    if (tid < 64) {
        float s = 0.f;
        #pragma unroll
        for (int p = 0; p < 17; p++) s += ws[WS_KSUMP + p*64 + tid];
        kss[tid] = s;
    }
    __syncthreads();

    const float* G = ws + WS_G;
    #pragma unroll
    for (int k = 0; k < 8; k++) {
        int slot = k*256 + tid;
        int m = slot >> 5, el4 = (slot & 31) * 4;
        int et = et0 + (el4 >> 6), eli4 = el4 & 63;
        size_t base = (size_t)(b*6 + et)*4096 + m*64 + eli4;
        float4 g0 = *(const float4*)&G[base];
        float4 g1 = *(const float4*)&G[base + (size_t) 96*4096];
        float4 g2 = *(const float4*)&G[base + (size_t)192*4096];
        float4 g3 = *(const float4*)&G[base + (size_t)288*4096];
        float km = kss[m];
        float4 c;
        c.x = ssc[el4+0]*(g0.x+g1.x+g2.x+g3.x) + ssh[el4+0]*km;
        c.y = ssc[el4+1]*(g0.y+g1.y+g2.y+g3.y) + ssh[el4+1]*km;
        c.z = ssc[el4+2]*(g0.z+g1.z+g2.z+g3.z) + ssh[el4+2]*km;
        c.w = ssc[el4+3]*(g0.w+g1.w+g2.w+g3.w) + ssh[el4+3]*km;
        *(float4*)&Cm[m*132 + el4] = c;
    }
    __syncthreads();

    const float* EWT = ws + WS_EWT;
    const float* evb = ws + WS_EVB;
    const int tx = tid & 31;
    const int ty = tid >> 5;
    for (int ti = 0; ti < 3; ti++) {
        const int tt0 = (tq*3 + ti) * 64;
        if (ti > 0) __syncthreads();
        #pragma unroll
        for (int k = 0; k < 4; k++) {
            int slot = k*256 + tid;
            int m = slot >> 4, t4 = (slot & 15)*4;
            int tp = tt0 + t4;
            float4 v;
            if (tp + 3 < PRED) v = *(const float4*)&EWT[(size_t)m*720 + tp];
            else {
                v = make_float4(0.f,0.f,0.f,0.f);
                if (tp   < PRED) v.x = EWT[(size_t)m*720 + tp];
                if (tp+1 < PRED) v.y = EWT[(size_t)m*720 + tp+1];
                if (tp+2 < PRED) v.z = EWT[(size_t)m*720 + tp+2];
            }
            *(float4*)&EWm[m*68 + t4] = v;
        }
        __syncthreads();

        float acc[8][4];
        #pragma unroll
        for (int i = 0; i < 8; i++)
            #pragma unroll
            for (int j = 0; j < 4; j++) acc[i][j] = 0.f;

        #pragma unroll 4
        for (int m = 0; m < 64; m++) {
            float4 c4 = *(const float4*)&Cm[m*132 + tx*4];
            float4 w0 = *(const float4*)&EWm[m*68 + ty*8];
            float4 w1 = *(const float4*)&EWm[m*68 + ty*8 + 4];
            acc[0][0]+=w0.x*c4.x; acc[0][1]+=w0.x*c4.y; acc[0][2]+=w0.x*c4.z; acc[0][3]+=w0.x*c4.w;
            acc[1][0]+=w0.y*c4.x; acc[1][1]+=w0.y*c4.y; acc[1][2]+=w0.y*c4.z; acc[1][3]+=w0.y*c4.w;
            acc[2][0]+=w0.z*c4.x; acc[2][1]+=w0.z*c4.y; acc[2][2]+=w0.z*c4.z; acc[2][3]+=w0.z*c4.w;
            acc[3][0]+=w0.w*c4.x; acc[3][1]+=w0.w*c4.y; acc[3][2]+=w0.w*c4.z; acc[3][3]+=w0.w*c4.w;
            acc[4][0]+=w1.x*c4.x; acc[4][1]+=w1.x*c4.y; acc[4][2]+=w1.x*c4.z; acc[4][3]+=w1.x*c4.w;
            acc[5][0]+=w1.y*c4.x; acc[5][1]+=w1.y*c4.y; acc[5][2]+=w1.y*c4.z; acc[5][3]+=w1.y*c4.w;
            acc[6][0]+=w1.z*c4.x; acc[6][1]+=w1.z*c4.y; acc[6][2]+=w1.z*c4.z; acc[6][3]+=w1.z*c4.w;
            acc[7][0]+=w1.w*c4.x; acc[7][1]+=w1.w*c4.y; acc[7][2]+=w1.w*c4.z; acc[7][3]+=w1.w*c4.w;
        }

        const int elb = tx*4;
        const int ebase = e0 + elb;
        #pragma unroll
        for (int i = 0; i < 8; i++) {
            int tp = tt0 + ty*8 + i;
            if (tp < PRED) {
                float ev = evb[tp];
                float* op = out + ((size_t)b*PRED + tp)*ENC;
                #pragma unroll
                for (int j = 0; j < 4; j++) {
                    int e = ebase + j;
                    if (e < ENC)
                        op[e] = (acc[i][j] + ev - sabe[elb+j]) * siaw[elb+j] * ssd[elb+j]
                                + smean[elb+j];
                }
            }
        }
    }
}

extern "C" void kernel_launch(void* const* d_in, const int* in_sizes, int n_in,
                              void* d_out, int out_size, void* d_ws, size_t ws_size,
                              hipStream_t stream)
{
    const float* x     = (const float*)d_in[0];
    const float* A     = (const float*)d_in[1];
    const float* Bv    = (const float*)d_in[2];
    const float* evalm = (const float*)d_in[3];
    const float* W     = (const float*)d_in[4];
    const float* bm    = (const float*)d_in[5];
    const float* aw    = (const float*)d_in[6];
    const float* ab    = (const float*)d_in[7];
    float* ws  = (float*)d_ws;
    float* out = (float*)d_out;

    prep    <<<17, 256, 0, stream>>>(A, Bv, ws);
    chainsEW<<<28, 256, 0, stream>>>(evalm, W, bm, ws);
    k2      <<<BATCH*6*4, 256, 0, stream>>>(x, ws);
    k3f     <<<192, 256, 0, stream>>>(aw, ab, ws, out);
}